// Round 12
// baseline (296.137 us; speedup 1.0000x reference)
//
#include <hip/hip_runtime.h>
#include <math.h>

#define BB 128
#define NN 256
#define EE 2048
#define BINS 16
#define GRID_PD (BB * 4)   // pairdot grid: must be <= co-resident capacity (1024)

// monotone float <-> uint encoding for atomic min/max on floats
__device__ __forceinline__ unsigned int fenc(float f) {
    unsigned int u = __float_as_uint(f);
    return (u & 0x80000000u) ? ~u : (u | 0x80000000u);
}
__device__ __forceinline__ float fdec(unsigned int u) {
    return (u & 0x80000000u) ? __uint_as_float(u & 0x7FFFFFFFu)
                             : __uint_as_float(~u);
}

// ---------------- CSR build, both sides: g in [0,2B). Block 0 also inits
// the histogram accumulators (counts, encoded lo/hi, ticket) for this replay. ----
__global__ void csr_kernel(const int* __restrict__ eq, const int* __restrict__ ec,
                           int* __restrict__ off, int* __restrict__ srcs,
                           float* __restrict__ wts,
                           unsigned int* __restrict__ lohiE,
                           unsigned int* __restrict__ ticket,
                           float* __restrict__ counts) {
    int g = blockIdx.x;                 // 0..2B-1
    int b = g < BB ? g : g - BB;
    const int* ei = g < BB ? eq : ec;
    int t = threadIdx.x;  // 256
    if (g == 0) {
        if (t < BINS) counts[t] = 0.f;
        if (t == 16) lohiE[0] = 0xFFFFFFFFu;   // min accumulator (encoded +inf)
        if (t == 17) lohiE[1] = 0u;            // max accumulator (encoded -inf)
        if (t == 18) ticket[0] = 0u;           // pairdot arrival counter
    }
    __shared__ int cnt[NN];
    __shared__ int sa[NN], sb[NN];
    __shared__ int cursor[NN];
    __shared__ float dvs[NN];
    cnt[t] = 0;
    __syncthreads();
    const int* src = ei + b * 2 * EE;
    const int* dst = src + EE;
    for (int e = t; e < EE; e += 256) atomicAdd(&cnt[dst[e]], 1);
    __syncthreads();
    dvs[t] = rsqrtf((float)cnt[t] + 1.0f);
    sa[t] = cnt[t];
    __syncthreads();
    int* pin = sa; int* pout = sb;
    for (int d = 1; d < NN; d <<= 1) {
        int v = pin[t];
        if (t >= d) v += pin[t - d];
        pout[t] = v;
        __syncthreads();
        int* tmp = pin; pin = pout; pout = tmp;
    }
    int excl = pin[t] - cnt[t];
    off[g * 257 + t] = excl;
    if (t == 255) off[g * 257 + 256] = EE;
    cursor[t] = excl;
    __syncthreads();
    for (int e = t; e < EE; e += 256) {
        int d = dst[e], s = src[e];
        int pos = atomicAdd(&cursor[d], 1);
        srcs[g * EE + pos] = s;
        wts[g * EE + pos] = dvs[s] * dvs[d];
    }
}

// ---------------- fused GCN layer — round-0's proven configuration (L1/L2) ----------------
// 512 thr, per-thread 4 rows x 4 cols, k-tile 16, separate hT, int esrc + LDS ewt.
// LDS ~70.1KB -> 2 blocks/CU. Plain __launch_bounds__(512) (min-waves forced VGPR=32
// + spills in R4; this config compiles to 64 VGPR, no spill — R0/R10 measured).
template<int FIN, int FOUT, bool RELU, int NSPLIT>
__global__ __launch_bounds__(512) void gcn_fused8(
        const float* __restrict__ X0, const float* __restrict__ X1,
        const float* __restrict__ W, const float* __restrict__ bias,
        const int* __restrict__ off, const int* __restrict__ srcs,
        const float* __restrict__ wts, float* __restrict__ OUT) {
    constexpr int CHUNKS = FOUT / 32;
    int blk = blockIdx.x;
    int g = blk % (2 * BB);
    int rest = blk / (2 * BB);
    int cb = (rest % CHUNKS) * 32;
    int half = rest / CHUNKS;          // 0..NSPLIT-1
    int t = threadIdx.x;

    __shared__ float hT[NN * 33];      // H chunk [n][c], stride 33
    __shared__ float xsT[16 * 260];    // X k-tile, k-major [k][n]
    __shared__ float wt[16 * 32];      // W k-tile [k][c]
    __shared__ int   eoff[NN + 1];
    __shared__ int   esrc[EE];
    __shared__ float ewt[EE];

    const float* xg = (g < BB) ? (X0 + (size_t)g * NN * FIN)
                               : (X1 + (size_t)(g - BB) * NN * FIN);
    const int* o = off + g * 257;
    const int* sr = srcs + (size_t)g * EE;
    const float* wg = wts + (size_t)g * EE;

    // stage edges + offsets (coalesced; completes during k-loop)
    for (int i = t; i < EE; i += 512) { esrc[i] = sr[i]; ewt[i] = wg[i]; }
    for (int i = t; i <= NN; i += 512) eoff[i] = o[i];

    int l = t & 63;        // lane -> node quad (rows 4l..4l+3)
    int wv = t >> 6;       // wave -> channel quad (cols 4wv..4wv+3)

    float acc[4][4];
#pragma unroll
    for (int i = 0; i < 4; i++)
#pragma unroll
        for (int j = 0; j < 4; j++) acc[i][j] = 0.f;

    int sn = t >> 1, qk = (t & 1) * 8;
    const float* xr = xg + sn * FIN + qk;
    float4 v0 = *(const float4*)xr;
    float4 v1 = *(const float4*)(xr + 4);
    float wreg = W[(t >> 5) * FOUT + cb + (t & 31)];

    for (int k0 = 0; k0 < FIN; k0 += 16) {
        xsT[(qk + 0) * 260 + sn] = v0.x;
        xsT[(qk + 1) * 260 + sn] = v0.y;
        xsT[(qk + 2) * 260 + sn] = v0.z;
        xsT[(qk + 3) * 260 + sn] = v0.w;
        xsT[(qk + 4) * 260 + sn] = v1.x;
        xsT[(qk + 5) * 260 + sn] = v1.y;
        xsT[(qk + 6) * 260 + sn] = v1.z;
        xsT[(qk + 7) * 260 + sn] = v1.w;
        wt[t] = wreg;
        __syncthreads();
        if (k0 + 16 < FIN) {
            xr += 16;
            v0 = *(const float4*)xr;
            v1 = *(const float4*)(xr + 4);
            wreg = W[(k0 + 16 + (t >> 5)) * FOUT + cb + (t & 31)];
        }
#pragma unroll
        for (int k = 0; k < 16; k++) {
            float4 xv = *(const float4*)&xsT[k * 260 + 4 * l];
            float4 wvv = *(const float4*)&wt[k * 32 + 4 * wv];
            acc[0][0] += xv.x * wvv.x; acc[0][1] += xv.x * wvv.y;
            acc[0][2] += xv.x * wvv.z; acc[0][3] += xv.x * wvv.w;
            acc[1][0] += xv.y * wvv.x; acc[1][1] += xv.y * wvv.y;
            acc[1][2] += xv.y * wvv.z; acc[1][3] += xv.y * wvv.w;
            acc[2][0] += xv.z * wvv.x; acc[2][1] += xv.z * wvv.y;
            acc[2][2] += xv.z * wvv.z; acc[2][3] += xv.z * wvv.w;
            acc[3][0] += xv.w * wvv.x; acc[3][1] += xv.w * wvv.y;
            acc[3][2] += xv.w * wvv.z; acc[3][3] += xv.w * wvv.w;
        }
        __syncthreads();
    }
#pragma unroll
    for (int i = 0; i < 4; i++)
#pragma unroll
        for (int j = 0; j < 4; j++)
            hT[(4 * l + i) * 33 + 4 * wv + j] = acc[i][j];
    __syncthreads();

    // CSR-gather aggregation: everything in LDS
    int c = t & 31, ng = t >> 5;
    float bb_ = bias[cb + c];
    float* outp = OUT + (size_t)g * NN * FOUT;
    constexpr int NSEG = NN / NSPLIT;
    int nlo = half * NSEG, nhi = nlo + NSEG;
    for (int n = nlo + ng; n < nhi; n += 16) {
        int j0 = eoff[n], j1 = eoff[n + 1];
        float a = 0.f;
        int j = j0;
        if (j < j1) {
            int s0 = esrc[j];
            float w0 = ewt[j];
            for (++j; j < j1; ++j) {
                int s1 = esrc[j];
                float w1 = ewt[j];
                a += hT[s0 * 33 + c] * w0;
                s0 = s1; w0 = w1;
            }
            a += hT[s0 * 33 + c] * w0;
        }
        float d0 = rsqrtf((float)(j1 - j0) + 1.0f);
        float val = a + hT[n * 33 + c] * d0 * d0 + bb_;
        if (RELU) val = fmaxf(val, 0.f);
        outp[n * FOUT + cb + c] = val;
    }
}

// ---------------- L3 + attention pooling fused: one block per graph ----------------
__global__ __launch_bounds__(512) void gcn3_att(
        const float* __restrict__ X0, const float* __restrict__ X1,
        const float* __restrict__ W, const float* __restrict__ bias,
        const float* __restrict__ Watt,
        const int* __restrict__ off, const int* __restrict__ srcs,
        const float* __restrict__ wts,
        float* __restrict__ O3, float* __restrict__ e12) {
    constexpr int FIN = 64, FOUT = 32;
    int g = blockIdx.x;                // 0..2B-1
    int t = threadIdx.x;

    __shared__ float hT[NN * 33];
    __shared__ float xsT[16 * 260];    // GEMM staging; reused as attpool scratch
    __shared__ float wt[16 * 32];
    __shared__ int   eoff[NN + 1];
    __shared__ int   esrc[EE];
    __shared__ float ewt[EE];
    // scratch overlays on xsT (first used AFTER the GEMM's final barrier):
    float* red    = xsT;               // [512]
    float* sc     = xsT + 512;         // [256]
    float* mean_s = xsT + 768;         // [32]
    float* ctx_s  = xsT + 800;         // [32]

    const float* xg = (g < BB) ? (X0 + (size_t)g * NN * FIN)
                               : (X1 + (size_t)(g - BB) * NN * FIN);
    const int* o = off + g * 257;
    const int* sr = srcs + (size_t)g * EE;
    const float* wg = wts + (size_t)g * EE;

    for (int i = t; i < EE; i += 512) { esrc[i] = sr[i]; ewt[i] = wg[i]; }
    for (int i = t; i <= NN; i += 512) eoff[i] = o[i];

    int l = t & 63;
    int wv = t >> 6;

    float acc[4][4];
#pragma unroll
    for (int i = 0; i < 4; i++)
#pragma unroll
        for (int j = 0; j < 4; j++) acc[i][j] = 0.f;

    int sn = t >> 1, qk = (t & 1) * 8;
    const float* xr = xg + sn * FIN + qk;
    float4 v0 = *(const float4*)xr;
    float4 v1 = *(const float4*)(xr + 4);
    float wreg = W[(t >> 5) * FOUT + (t & 31)];

    for (int k0 = 0; k0 < FIN; k0 += 16) {
        xsT[(qk + 0) * 260 + sn] = v0.x;
        xsT[(qk + 1) * 260 + sn] = v0.y;
        xsT[(qk + 2) * 260 + sn] = v0.z;
        xsT[(qk + 3) * 260 + sn] = v0.w;
        xsT[(qk + 4) * 260 + sn] = v1.x;
        xsT[(qk + 5) * 260 + sn] = v1.y;
        xsT[(qk + 6) * 260 + sn] = v1.z;
        xsT[(qk + 7) * 260 + sn] = v1.w;
        wt[t] = wreg;
        __syncthreads();
        if (k0 + 16 < FIN) {
            xr += 16;
            v0 = *(const float4*)xr;
            v1 = *(const float4*)(xr + 4);
            wreg = W[(k0 + 16 + (t >> 5)) * FOUT + (t & 31)];
        }
#pragma unroll
        for (int k = 0; k < 16; k++) {
            float4 xv = *(const float4*)&xsT[k * 260 + 4 * l];
            float4 wvv = *(const float4*)&wt[k * 32 + 4 * wv];
            acc[0][0] += xv.x * wvv.x; acc[0][1] += xv.x * wvv.y;
            acc[0][2] += xv.x * wvv.z; acc[0][3] += xv.x * wvv.w;
            acc[1][0] += xv.y * wvv.x; acc[1][1] += xv.y * wvv.y;
            acc[1][2] += xv.y * wvv.z; acc[1][3] += xv.y * wvv.w;
            acc[2][0] += xv.z * wvv.x; acc[2][1] += xv.z * wvv.y;
            acc[2][2] += xv.z * wvv.z; acc[2][3] += xv.z * wvv.w;
            acc[3][0] += xv.w * wvv.x; acc[3][1] += xv.w * wvv.y;
            acc[3][2] += xv.w * wvv.z; acc[3][3] += xv.w * wvv.w;
        }
        __syncthreads();
    }
#pragma unroll
    for (int i = 0; i < 4; i++)
#pragma unroll
        for (int j = 0; j < 4; j++)
            hT[(4 * l + i) * 33 + 4 * wv + j] = acc[i][j];
    __syncthreads();   // GEMM done: xsT free for scratch reuse

    // gather -> registers A[16]; thread (c=t&31, ng=t>>5) owns nodes ng*16..ng*16+15
    int c = t & 31, ng = t >> 5;
    float bb_ = bias[c];
    float A[16];
#pragma unroll
    for (int i = 0; i < 16; i++) {
        int n = ng * 16 + i;
        int j0 = eoff[n], j1 = eoff[n + 1];
        float a = 0.f;
        int j = j0;
        if (j < j1) {
            int s0 = esrc[j];
            float w0 = ewt[j];
            for (++j; j < j1; ++j) {
                int s1 = esrc[j];
                float w1 = ewt[j];
                a += hT[s0 * 33 + c] * w0;
                s0 = s1; w0 = w1;
            }
            a += hT[s0 * 33 + c] * w0;
        }
        float d0 = rsqrtf((float)(j1 - j0) + 1.0f);
        A[i] = a + hT[n * 33 + c] * d0 * d0 + bb_;   // no ReLU on L3
    }

    // ---- attention pooling (in-block) ----
    {
        float ps = 0.f;
#pragma unroll
        for (int i = 0; i < 16; i++) ps += A[i];
        red[t] = ps;
    }
    __syncthreads();
    if (t < 32) {
        float m = 0.f;
        for (int p = 0; p < 16; p++) m += red[p * 32 + t];
        mean_s[t] = m / (float)NN;
    }
    __syncthreads();
    if (t < 32) {
        float a = 0.f;
        for (int f = 0; f < 32; f++) a += mean_s[f] * Watt[t * 32 + f];
        ctx_s[t] = tanhf(a);
    }
    __syncthreads();
    {
        float cv = ctx_s[c];
#pragma unroll
        for (int i = 0; i < 16; i++) {
            float v = A[i] * cv;
            v += __shfl_xor(v, 16);
            v += __shfl_xor(v, 8);
            v += __shfl_xor(v, 4);
            v += __shfl_xor(v, 2);
            v += __shfl_xor(v, 1);
            if (c == 0) sc[ng * 16 + i] = 1.f / (1.f + expf(-v));
        }
    }
    __syncthreads();
    {
        float pp = 0.f;
        float* outp = O3 + (size_t)g * NN * 32;
#pragma unroll
        for (int i = 0; i < 16; i++) {
            int n = ng * 16 + i;
            pp += A[i] * sc[n];
            outp[n * 32 + c] = A[i];
        }
        red[t] = pp;
    }
    __syncthreads();
    if (t < 32) {
        float s = 0.f;
        for (int p = 0; p < 16; p++) s += red[p * 32 + t];
        e12[g * 32 + t] = s;
    }
}

// ---------------- single-pass pairdot: dots once, grid-sync, histogram ----------------
// 128x128 tile, 8x8 per thread, f-major LDS. Co-residency guaranteed by arithmetic:
// __launch_bounds__(256,4) caps VGPR at 128 (4 waves/SIMD) and LDS is 36.1KB <= 40KB
// -> 4 blocks/CU x 256 CU = 1024 slots >= GRID_PD=512, so all blocks are scheduled
// before any waits. Cross-block data uses device-scope atomics + threadfence only.
__global__ __launch_bounds__(256, 4) void pairdot_all(
        const float* __restrict__ Q, const float* __restrict__ C,
        unsigned int* __restrict__ lohiE, unsigned int* __restrict__ ticket,
        float* __restrict__ counts) {
    int blk = blockIdx.x;
    int b = blk >> 2;
    int tq = (blk >> 1) & 1, tc = blk & 1;
    __shared__ float qsT[32 * 132];
    __shared__ float csT[32 * 132];
    int t = threadIdx.x;
    {
        int n = t >> 1, f0 = (t & 1) * 16;
        const float* qp = Q + ((size_t)b * NN + tq * 128 + n) * 32 + f0;
        const float* cp = C + ((size_t)b * NN + tc * 128 + n) * 32 + f0;
        float qa16[16], ca16[16];
        *(float4*)&qa16[0]  = *(const float4*)(qp);
        *(float4*)&qa16[4]  = *(const float4*)(qp + 4);
        *(float4*)&qa16[8]  = *(const float4*)(qp + 8);
        *(float4*)&qa16[12] = *(const float4*)(qp + 12);
        *(float4*)&ca16[0]  = *(const float4*)(cp);
        *(float4*)&ca16[4]  = *(const float4*)(cp + 4);
        *(float4*)&ca16[8]  = *(const float4*)(cp + 8);
        *(float4*)&ca16[12] = *(const float4*)(cp + 12);
#pragma unroll
        for (int m = 0; m < 16; m++) {
            qsT[(f0 + m) * 132 + n] = qa16[m];
            csT[(f0 + m) * 132 + n] = ca16[m];
        }
    }
    __syncthreads();
    int rg = (t >> 4) * 4, cg = (t & 15) * 4;
    float acc[8][8];
#pragma unroll
    for (int i = 0; i < 8; i++)
#pragma unroll
        for (int j = 0; j < 8; j++) acc[i][j] = 0.f;
#pragma unroll 2
    for (int f = 0; f < 32; f++) {
        float4 qa = *(const float4*)&qsT[f * 132 + rg];
        float4 qb = *(const float4*)&qsT[f * 132 + 64 + rg];
        float4 ca = *(const float4*)&csT[f * 132 + cg];
        float4 cb = *(const float4*)&csT[f * 132 + 64 + cg];
        float qv[8] = {qa.x, qa.y, qa.z, qa.w, qb.x, qb.y, qb.z, qb.w};
        float cv[8] = {ca.x, ca.y, ca.z, ca.w, cb.x, cb.y, cb.z, cb.w};
#pragma unroll
        for (int i = 0; i < 8; i++)
#pragma unroll
            for (int j = 0; j < 8; j++) acc[i][j] += qv[i] * cv[j];
    }

    // block min/max
    float lmin = acc[0][0], lmax = acc[0][0];
#pragma unroll
    for (int i = 0; i < 8; i++)
#pragma unroll
        for (int j = 0; j < 8; j++) {
            lmin = fminf(lmin, acc[i][j]);
            lmax = fmaxf(lmax, acc[i][j]);
        }
    __shared__ float rmin[256], rmax[256];
    __shared__ float lohi_s[2];
    rmin[t] = lmin; rmax[t] = lmax;
    __syncthreads();
    for (int s = 128; s > 0; s >>= 1) {
        if (t < s) { rmin[t] = fminf(rmin[t], rmin[t + s]); rmax[t] = fmaxf(rmax[t], rmax[t + s]); }
        __syncthreads();
    }
    if (t == 0) {
        atomicMin(&lohiE[0], fenc(rmin[0]));
        atomicMax(&lohiE[1], fenc(rmax[0]));
        __threadfence();                     // publish before arrival
        atomicAdd(ticket, 1u);
        while (atomicAdd(ticket, 0u) < (unsigned)GRID_PD) {   // device-coherent poll
            __builtin_amdgcn_s_sleep(8);
        }
        __threadfence();
        lohi_s[0] = fdec(atomicAdd(&lohiE[0], 0u));   // coherent reads
        lohi_s[1] = fdec(atomicAdd(&lohiE[1], 0u));
    }
    __syncthreads();

    // histogram with retained accumulators
    float lo = lohi_s[0], hi = lohi_s[1];
    float scale = (float)BINS / (hi - lo);
    int lane = t & 63;
    int cnt = 0;   // lane L accumulates count for bin (L & 15)
#pragma unroll
    for (int i = 0; i < 8; i++)
#pragma unroll
        for (int j = 0; j < 8; j++) {
            int idx = (int)floorf((acc[i][j] - lo) * scale);
            idx = min(max(idx, 0), BINS - 1);
            unsigned long long b0 = __ballot((idx & 1) != 0);
            unsigned long long b1 = __ballot((idx & 2) != 0);
            unsigned long long b2 = __ballot((idx & 4) != 0);
            unsigned long long b3 = __ballot((idx & 8) != 0);
            unsigned long long msk = ((lane & 1) ? b0 : ~b0);
            msk &= ((lane & 2) ? b1 : ~b1);
            msk &= ((lane & 4) ? b2 : ~b2);
            msk &= ((lane & 8) ? b3 : ~b3);
            cnt += __popcll(msk);
        }
    __shared__ float wbins[4][BINS];
    int wave = t >> 6;
    if (lane < BINS) wbins[wave][lane] = (float)cnt;
    __syncthreads();
    if (t < BINS) {
        atomicAdd(&counts[t], wbins[0][t] + wbins[1][t] + wbins[2][t] + wbins[3][t]);
    }
}

// ---------------- NTN + histogram concat + fc1 + fc2 head ----------------
__global__ void final_kernel(const float* __restrict__ e1, const float* __restrict__ e2,
                             const float* __restrict__ ntnW, const float* __restrict__ ntnV,
                             const float* __restrict__ ntnb, const float* __restrict__ counts,
                             const float* __restrict__ fc1W, const float* __restrict__ fc1b,
                             const float* __restrict__ fc2W, const float* __restrict__ fc2b,
                             float* __restrict__ out) {
    int b = blockIdx.x;
    int t = threadIdx.x;
    __shared__ float a1[32], a2[32], red[256], z[32], u[16];
    if (t < 32) a1[t] = e1[b * 32 + t];
    else if (t < 64) a2[t - 32] = e2[b * 32 + t - 32];
    __syncthreads();
    int tt = t >> 4, g = t & 15;
    float p = 0.f;
#pragma unroll
    for (int ii = 0; ii < 2; ii++) {
        int i = g + 16 * ii;
        float d = 0.f;
        const float* wr = ntnW + (tt * 32 + i) * 32;
        for (int j = 0; j < 32; j++) d += wr[j] * a2[j];
        p += a1[i] * d;
    }
    red[t] = p;
    __syncthreads();
    if (t < 16) {
        float s = 0.f;
        for (int g2 = 0; g2 < 16; g2++) s += red[t * 16 + g2];
        float lin = ntnb[t];
        for (int i = 0; i < 32; i++) lin += ntnV[t * 64 + i] * a1[i];
        for (int i = 0; i < 32; i++) lin += ntnV[t * 64 + 32 + i] * a2[i];
        z[t] = fmaxf(s + lin, 0.f);
    } else if (t < 32) {
        float tot = 0.f;
        for (int i = 0; i < BINS; i++) tot += counts[i];
        z[t] = counts[t - 16] / tot;
    }
    __syncthreads();
    if (t < 16) {
        float a = fc1b[t];
        for (int i = 0; i < 32; i++) a += fc1W[t * 32 + i] * z[i];
        u[t] = fmaxf(a, 0.f);
    }
    __syncthreads();
    if (t == 0) {
        float a = fc2b[0];
        for (int i = 0; i < 16; i++) a += fc2W[i] * u[i];
        out[b] = 1.f / (1.f + expf(-a));
    }
}

extern "C" void kernel_launch(void* const* d_in, const int* in_sizes, int n_in,
                              void* d_out, int out_size, void* d_ws, size_t ws_size,
                              hipStream_t stream) {
    const float* xq   = (const float*)d_in[0];
    const float* xc   = (const float*)d_in[1];
    const int*   eq   = (const int*)d_in[2];
    const int*   ec   = (const int*)d_in[3];
    const float* W1   = (const float*)d_in[4];
    const float* b1   = (const float*)d_in[5];
    const float* W2   = (const float*)d_in[6];
    const float* b2   = (const float*)d_in[7];
    const float* W3   = (const float*)d_in[8];
    const float* b3   = (const float*)d_in[9];
    const float* Watt = (const float*)d_in[10];
    const float* ntnW = (const float*)d_in[11];
    const float* ntnV = (const float*)d_in[12];
    const float* ntnb = (const float*)d_in[13];
    const float* fc1W = (const float*)d_in[14];
    const float* fc1b = (const float*)d_in[15];
    const float* fc2W = (const float*)d_in[16];
    const float* fc2b = (const float*)d_in[17];
    float* out = (float*)d_out;
    float* ws  = (float*)d_ws;

    // ---- workspace layout (float indices), round-0 proven footprint ----
    float* O3   = ws;                           // 2*B*N*32  = 2097152
    float* e12  = O3 + 2097152;                 // 2*B*32    = 8192
    unsigned int* ticket = (unsigned int*)(e12 + 8192);  // 1 (in old bmin region)
    float* bmax = e12 + 8192 + 2048;            // 2048 (unused, layout keep)
    unsigned int* lohiE = (unsigned int*)(bmax + 2048);  // 2 encoded uints
    float* cntw = (float*)(lohiE + 2);          // 16
    int*   off  = (int*)(ws + 2109504);         // 2B*257 = 65792
    int*   srcs = off + 65792;                  // 2B*E = 524288
    float* wts  = (float*)(srcs + 524288);      // 524288
    float* O1   = ws + 3223872;                 // 2*B*N*128 = 8388608
    float* O2   = O1 + 8388608;                 // 2*B*N*64  = 4194304

    float* O3Q = O3;
    float* O3C = O3 + (size_t)BB * NN * 32;
    float* e1w = e12;
    float* e2w = e12 + BB * 32;
    (void)bmax;

    csr_kernel<<<2 * BB, 256, 0, stream>>>(eq, ec, off, srcs, wts, lohiE, ticket, cntw);

    gcn_fused8<128, 128, true, 1><<<4 * 2 * BB, 512, 0, stream>>>(
        xq, xc, W1, b1, off, srcs, wts, O1);
    gcn_fused8<128, 64, true, 1><<<2 * 2 * BB, 512, 0, stream>>>(
        O1, O1 + (size_t)BB * NN * 128, W2, b2, off, srcs, wts, O2);

    // L3 + attention pooling fused (writes O3 and e12)
    gcn3_att<<<2 * BB, 512, 0, stream>>>(
        O2, O2 + (size_t)BB * NN * 64, W3, b3, Watt, off, srcs, wts, O3, e12);

    // single-pass pairdot: dots once -> min/max atomics -> co-resident spin -> hist
    pairdot_all<<<GRID_PD, 256, 0, stream>>>(O3Q, O3C, lohiE, ticket, cntw);

    final_kernel<<<BB, 256, 0, stream>>>(e1w, e2w, ntnW, ntnV, ntnb, cntw,
                                         fc1W, fc1b, fc2W, fc2b, out);
}

// Round 13
// 278.019 us; speedup vs baseline: 1.0652x; 1.0652x over previous
//
#include <hip/hip_runtime.h>
#include <math.h>

#define BB 128
#define NN 256
#define EE 2048
#define BINS 16

// monotone float <-> uint encoding for atomic min/max on floats
__device__ __forceinline__ unsigned int fenc(float f) {
    unsigned int u = __float_as_uint(f);
    return (u & 0x80000000u) ? ~u : (u | 0x80000000u);
}
__device__ __forceinline__ float fdec(unsigned int u) {
    return (u & 0x80000000u) ? __uint_as_float(u & 0x7FFFFFFFu)
                             : __uint_as_float(~u);
}

// ---------------- CSR build, both sides: g in [0,2B). Block 0 also inits
// the histogram accumulators (counts, encoded lo/hi) for this graph replay. ----
__global__ void csr_kernel(const int* __restrict__ eq, const int* __restrict__ ec,
                           int* __restrict__ off, int* __restrict__ srcs,
                           float* __restrict__ wts,
                           unsigned int* __restrict__ lohiE,
                           float* __restrict__ counts) {
    int g = blockIdx.x;                 // 0..2B-1
    int b = g < BB ? g : g - BB;
    const int* ei = g < BB ? eq : ec;
    int t = threadIdx.x;  // 256
    if (g == 0) {
        if (t < BINS) counts[t] = 0.f;
        if (t == 16) lohiE[0] = 0xFFFFFFFFu;   // min accumulator (encoded +inf)
        if (t == 17) lohiE[1] = 0u;            // max accumulator (encoded -inf)
    }
    __shared__ int cnt[NN];
    __shared__ int sa[NN], sb[NN];
    __shared__ int cursor[NN];
    __shared__ float dvs[NN];
    cnt[t] = 0;
    __syncthreads();
    const int* src = ei + b * 2 * EE;
    const int* dst = src + EE;
    for (int e = t; e < EE; e += 256) atomicAdd(&cnt[dst[e]], 1);
    __syncthreads();
    dvs[t] = rsqrtf((float)cnt[t] + 1.0f);
    sa[t] = cnt[t];
    __syncthreads();
    int* pin = sa; int* pout = sb;
    for (int d = 1; d < NN; d <<= 1) {
        int v = pin[t];
        if (t >= d) v += pin[t - d];
        pout[t] = v;
        __syncthreads();
        int* tmp = pin; pin = pout; pout = tmp;
    }
    int excl = pin[t] - cnt[t];
    off[g * 257 + t] = excl;
    if (t == 255) off[g * 257 + 256] = EE;
    cursor[t] = excl;
    __syncthreads();
    for (int e = t; e < EE; e += 256) {
        int d = dst[e], s = src[e];
        int pos = atomicAdd(&cursor[d], 1);
        srcs[g * EE + pos] = s;
        wts[g * EE + pos] = dvs[s] * dvs[d];
    }
}

// ---------------- fused GCN layer — round-0's proven 74.5µs configuration ----------------
// 512 thr, per-thread 4 rows x 4 cols, k-tile 16, separate hT, int esrc + LDS ewt.
// LDS ~70.1KB -> 2 blocks/CU. Plain __launch_bounds__(512) (min-waves forced VGPR=32
// + spills in R4; this config compiles to 64 VGPR, no spill — R0/R10 measured).
// NSPLIT only splits the gather node-range (duplicate GEMM) to widen small layers' grids.
// NOTE (session ceiling): per wave-k this body moves ~1KB lane-varying LDS for 1024
// FMAs — exactly the CU's 128 B/cy : 128 FMA/cy balance — so VALUBusy caps ~48%.
// Five scheduling attacks (occupancy 8->32 waves, 4x8 acc, dbuf, k-tile 32, W-once)
// all confirmed the cap. Do not re-tune this loop without new counter evidence.
template<int FIN, int FOUT, bool RELU, int NSPLIT>
__global__ __launch_bounds__(512) void gcn_fused8(
        const float* __restrict__ X0, const float* __restrict__ X1,
        const float* __restrict__ W, const float* __restrict__ bias,
        const int* __restrict__ off, const int* __restrict__ srcs,
        const float* __restrict__ wts, float* __restrict__ OUT) {
    constexpr int CHUNKS = FOUT / 32;
    int blk = blockIdx.x;
    int g = blk % (2 * BB);
    int rest = blk / (2 * BB);
    int cb = (rest % CHUNKS) * 32;
    int half = rest / CHUNKS;          // 0..NSPLIT-1
    int t = threadIdx.x;

    __shared__ float hT[NN * 33];      // H chunk [n][c], stride 33
    __shared__ float xsT[16 * 260];    // X k-tile, k-major [k][n]
    __shared__ float wt[16 * 32];      // W k-tile [k][c]
    __shared__ int   eoff[NN + 1];
    __shared__ int   esrc[EE];
    __shared__ float ewt[EE];

    const float* xg = (g < BB) ? (X0 + (size_t)g * NN * FIN)
                               : (X1 + (size_t)(g - BB) * NN * FIN);
    const int* o = off + g * 257;
    const int* sr = srcs + (size_t)g * EE;
    const float* wg = wts + (size_t)g * EE;

    // stage edges + offsets (coalesced; completes during k-loop)
    for (int i = t; i < EE; i += 512) { esrc[i] = sr[i]; ewt[i] = wg[i]; }
    for (int i = t; i <= NN; i += 512) eoff[i] = o[i];

    int l = t & 63;        // lane -> node quad (rows 4l..4l+3)
    int wv = t >> 6;       // wave -> channel quad (cols 4wv..4wv+3)

    float acc[4][4];
#pragma unroll
    for (int i = 0; i < 4; i++)
#pragma unroll
        for (int j = 0; j < 4; j++) acc[i][j] = 0.f;

    int sn = t >> 1, qk = (t & 1) * 8;
    const float* xr = xg + sn * FIN + qk;
    float4 v0 = *(const float4*)xr;
    float4 v1 = *(const float4*)(xr + 4);
    float wreg = W[(t >> 5) * FOUT + cb + (t & 31)];

    for (int k0 = 0; k0 < FIN; k0 += 16) {
        xsT[(qk + 0) * 260 + sn] = v0.x;
        xsT[(qk + 1) * 260 + sn] = v0.y;
        xsT[(qk + 2) * 260 + sn] = v0.z;
        xsT[(qk + 3) * 260 + sn] = v0.w;
        xsT[(qk + 4) * 260 + sn] = v1.x;
        xsT[(qk + 5) * 260 + sn] = v1.y;
        xsT[(qk + 6) * 260 + sn] = v1.z;
        xsT[(qk + 7) * 260 + sn] = v1.w;
        wt[t] = wreg;
        __syncthreads();
        if (k0 + 16 < FIN) {
            xr += 16;
            v0 = *(const float4*)xr;
            v1 = *(const float4*)(xr + 4);
            wreg = W[(k0 + 16 + (t >> 5)) * FOUT + cb + (t & 31)];
        }
#pragma unroll
        for (int k = 0; k < 16; k++) {
            float4 xv = *(const float4*)&xsT[k * 260 + 4 * l];
            float4 wvv = *(const float4*)&wt[k * 32 + 4 * wv];
            acc[0][0] += xv.x * wvv.x; acc[0][1] += xv.x * wvv.y;
            acc[0][2] += xv.x * wvv.z; acc[0][3] += xv.x * wvv.w;
            acc[1][0] += xv.y * wvv.x; acc[1][1] += xv.y * wvv.y;
            acc[1][2] += xv.y * wvv.z; acc[1][3] += xv.y * wvv.w;
            acc[2][0] += xv.z * wvv.x; acc[2][1] += xv.z * wvv.y;
            acc[2][2] += xv.z * wvv.z; acc[2][3] += xv.z * wvv.w;
            acc[3][0] += xv.w * wvv.x; acc[3][1] += xv.w * wvv.y;
            acc[3][2] += xv.w * wvv.z; acc[3][3] += xv.w * wvv.w;
        }
        __syncthreads();
    }
#pragma unroll
    for (int i = 0; i < 4; i++)
#pragma unroll
        for (int j = 0; j < 4; j++)
            hT[(4 * l + i) * 33 + 4 * wv + j] = acc[i][j];
    __syncthreads();

    // CSR-gather aggregation: everything in LDS (R0's 1-deep pipelined form)
    int c = t & 31, ng = t >> 5;
    float bb_ = bias[cb + c];
    float* outp = OUT + (size_t)g * NN * FOUT;
    constexpr int NSEG = NN / NSPLIT;
    int nlo = half * NSEG, nhi = nlo + NSEG;
    for (int n = nlo + ng; n < nhi; n += 16) {
        int j0 = eoff[n], j1 = eoff[n + 1];
        float a = 0.f;
        int j = j0;
        if (j < j1) {
            int s0 = esrc[j];
            float w0 = ewt[j];
            for (++j; j < j1; ++j) {
                int s1 = esrc[j];
                float w1 = ewt[j];
                a += hT[s0 * 33 + c] * w0;
                s0 = s1; w0 = w1;
            }
            a += hT[s0 * 33 + c] * w0;
        }
        float d0 = rsqrtf((float)(j1 - j0) + 1.0f);
        float val = a + hT[n * 33 + c] * d0 * d0 + bb_;
        if (RELU) val = fmaxf(val, 0.f);
        outp[n * FOUT + cb + c] = val;
    }
}

// ---------------- attention pooling (both sides): one block per graph ----------------
__global__ void attpool_kernel(const float* __restrict__ X, const float* __restrict__ Watt,
                               float* __restrict__ e) {
    int g = blockIdx.x;   // 0..2B-1
    int t = threadIdx.x;
    __shared__ float xs[NN * 33];
    __shared__ float red[256];
    __shared__ float mean_s[32], ctx_s[32], sc[NN];
    const float* x = X + (size_t)g * NN * 32;
    for (int i = t; i < NN * 32; i += 256) { int n = i >> 5, c = i & 31; xs[n * 33 + c] = x[i]; }
    __syncthreads();
    {
        int c = t & 31, p = t >> 5;
        float s = 0.f;
        for (int n = p * 32; n < (p + 1) * 32; n++) s += xs[n * 33 + c];
        red[t] = s;
    }
    __syncthreads();
    if (t < 32) {
        float m = 0.f;
        for (int p = 0; p < 8; p++) m += red[p * 32 + t];
        mean_s[t] = m / (float)NN;
    }
    __syncthreads();
    if (t < 32) {
        float a = 0.f;
        for (int f = 0; f < 32; f++) a += mean_s[f] * Watt[t * 32 + f];
        ctx_s[t] = tanhf(a);
    }
    __syncthreads();
    {
        float a = 0.f;
        for (int f = 0; f < 32; f++) a += xs[t * 33 + f] * ctx_s[f];
        sc[t] = 1.f / (1.f + expf(-a));
    }
    __syncthreads();
    {
        int c = t & 31, p = t >> 5;
        float s = 0.f;
        for (int n = p * 32; n < (p + 1) * 32; n++) s += xs[n * 33 + c] * sc[n];
        red[t] = s;
    }
    __syncthreads();
    if (t < 32) {
        float s = 0.f;
        for (int p = 0; p < 8; p++) s += red[p * 32 + t];
        e[g * 32 + t] = s;
    }
}

// ---------------- pairwise dots: 128x128 tile, 8x8 per thread, f-major LDS ----------------
#define PD_STAGE_AND_DOT \
    int blk = blockIdx.x; \
    int b = blk >> 2; \
    int tq = (blk >> 1) & 1, tc = blk & 1; \
    __shared__ float qsT[32 * 132]; \
    __shared__ float csT[32 * 132]; \
    int t = threadIdx.x; \
    { \
        int n = t >> 1, f0 = (t & 1) * 16; \
        const float* qp = Q + ((size_t)b * NN + tq * 128 + n) * 32 + f0; \
        const float* cp = C + ((size_t)b * NN + tc * 128 + n) * 32 + f0; \
        float qa16[16], ca16[16]; \
        *(float4*)&qa16[0]  = *(const float4*)(qp); \
        *(float4*)&qa16[4]  = *(const float4*)(qp + 4); \
        *(float4*)&qa16[8]  = *(const float4*)(qp + 8); \
        *(float4*)&qa16[12] = *(const float4*)(qp + 12); \
        *(float4*)&ca16[0]  = *(const float4*)(cp); \
        *(float4*)&ca16[4]  = *(const float4*)(cp + 4); \
        *(float4*)&ca16[8]  = *(const float4*)(cp + 8); \
        *(float4*)&ca16[12] = *(const float4*)(cp + 12); \
        _Pragma("unroll") \
        for (int m = 0; m < 16; m++) { \
            qsT[(f0 + m) * 132 + n] = qa16[m]; \
            csT[(f0 + m) * 132 + n] = ca16[m]; \
        } \
    } \
    __syncthreads(); \
    int rg = (t >> 4) * 4, cg = (t & 15) * 4; \
    float acc[8][8]; \
    _Pragma("unroll") \
    for (int i = 0; i < 8; i++) \
        _Pragma("unroll") \
        for (int j = 0; j < 8; j++) acc[i][j] = 0.f; \
    _Pragma("unroll 2") \
    for (int f = 0; f < 32; f++) { \
        float4 qa = *(const float4*)&qsT[f * 132 + rg]; \
        float4 qb = *(const float4*)&qsT[f * 132 + 64 + rg]; \
        float4 ca = *(const float4*)&csT[f * 132 + cg]; \
        float4 cb = *(const float4*)&csT[f * 132 + 64 + cg]; \
        float qv[8] = {qa.x, qa.y, qa.z, qa.w, qb.x, qb.y, qb.z, qb.w}; \
        float cv[8] = {ca.x, ca.y, ca.z, ca.w, cb.x, cb.y, cb.z, cb.w}; \
        _Pragma("unroll") \
        for (int i = 0; i < 8; i++) \
            _Pragma("unroll") \
            for (int j = 0; j < 8; j++) acc[i][j] += qv[i] * cv[j]; \
    }

// pass 1: min/max -> device atomics on encoded uints (no separate reduce kernel)
__global__ __launch_bounds__(256, 4) void pairdot_minmax(
        const float* __restrict__ Q, const float* __restrict__ C,
        unsigned int* __restrict__ lohiE) {
    PD_STAGE_AND_DOT
    float lmin = acc[0][0], lmax = acc[0][0];
#pragma unroll
    for (int i = 0; i < 8; i++)
#pragma unroll
        for (int j = 0; j < 8; j++) {
            lmin = fminf(lmin, acc[i][j]);
            lmax = fmaxf(lmax, acc[i][j]);
        }
    __shared__ float rmin[256], rmax[256];
    rmin[t] = lmin; rmax[t] = lmax;
    __syncthreads();
    for (int s = 128; s > 0; s >>= 1) {
        if (t < s) { rmin[t] = fminf(rmin[t], rmin[t + s]); rmax[t] = fmaxf(rmax[t], rmax[t + s]); }
        __syncthreads();
    }
    if (t == 0) {
        atomicMin(&lohiE[0], fenc(rmin[0]));
        atomicMax(&lohiE[1], fenc(rmax[0]));
    }
}

// pass 2: recompute dots, bit-sliced ballot histogram
__global__ __launch_bounds__(256, 4) void pairdot_hist(
        const float* __restrict__ Q, const float* __restrict__ C,
        const unsigned int* __restrict__ lohiE, float* __restrict__ counts) {
    PD_STAGE_AND_DOT
    float lo = fdec(lohiE[0]), hi = fdec(lohiE[1]);
    float scale = (float)BINS / (hi - lo);
    int lane = t & 63;
    int cnt = 0;   // lane L accumulates count for bin (L & 15)
#pragma unroll
    for (int i = 0; i < 8; i++)
#pragma unroll
        for (int j = 0; j < 8; j++) {
            int idx = (int)floorf((acc[i][j] - lo) * scale);
            idx = min(max(idx, 0), BINS - 1);
            unsigned long long b0 = __ballot((idx & 1) != 0);
            unsigned long long b1 = __ballot((idx & 2) != 0);
            unsigned long long b2 = __ballot((idx & 4) != 0);
            unsigned long long b3 = __ballot((idx & 8) != 0);
            unsigned long long msk = ((lane & 1) ? b0 : ~b0);
            msk &= ((lane & 2) ? b1 : ~b1);
            msk &= ((lane & 4) ? b2 : ~b2);
            msk &= ((lane & 8) ? b3 : ~b3);
            cnt += __popcll(msk);
        }
    __shared__ float wbins[4][BINS];
    int wave = t >> 6;
    if (lane < BINS) wbins[wave][lane] = (float)cnt;
    __syncthreads();
    if (t < BINS) {
        atomicAdd(&counts[t], wbins[0][t] + wbins[1][t] + wbins[2][t] + wbins[3][t]);
    }
}

// ---------------- NTN + histogram concat + fc1 + fc2 head ----------------
__global__ void final_kernel(const float* __restrict__ e1, const float* __restrict__ e2,
                             const float* __restrict__ ntnW, const float* __restrict__ ntnV,
                             const float* __restrict__ ntnb, const float* __restrict__ counts,
                             const float* __restrict__ fc1W, const float* __restrict__ fc1b,
                             const float* __restrict__ fc2W, const float* __restrict__ fc2b,
                             float* __restrict__ out) {
    int b = blockIdx.x;
    int t = threadIdx.x;
    __shared__ float a1[32], a2[32], red[256], z[32], u[16];
    if (t < 32) a1[t] = e1[b * 32 + t];
    else if (t < 64) a2[t - 32] = e2[b * 32 + t - 32];
    __syncthreads();
    int tt = t >> 4, g = t & 15;
    float p = 0.f;
#pragma unroll
    for (int ii = 0; ii < 2; ii++) {
        int i = g + 16 * ii;
        float d = 0.f;
        const float* wr = ntnW + (tt * 32 + i) * 32;
        for (int j = 0; j < 32; j++) d += wr[j] * a2[j];
        p += a1[i] * d;
    }
    red[t] = p;
    __syncthreads();
    if (t < 16) {
        float s = 0.f;
        for (int g2 = 0; g2 < 16; g2++) s += red[t * 16 + g2];
        float lin = ntnb[t];
        for (int i = 0; i < 32; i++) lin += ntnV[t * 64 + i] * a1[i];
        for (int i = 0; i < 32; i++) lin += ntnV[t * 64 + 32 + i] * a2[i];
        z[t] = fmaxf(s + lin, 0.f);
    } else if (t < 32) {
        float tot = 0.f;
        for (int i = 0; i < BINS; i++) tot += counts[i];
        z[t] = counts[t - 16] / tot;
    }
    __syncthreads();
    if (t < 16) {
        float a = fc1b[t];
        for (int i = 0; i < 32; i++) a += fc1W[t * 32 + i] * z[i];
        u[t] = fmaxf(a, 0.f);
    }
    __syncthreads();
    if (t == 0) {
        float a = fc2b[0];
        for (int i = 0; i < 16; i++) a += fc2W[i] * u[i];
        out[b] = 1.f / (1.f + expf(-a));
    }
}

extern "C" void kernel_launch(void* const* d_in, const int* in_sizes, int n_in,
                              void* d_out, int out_size, void* d_ws, size_t ws_size,
                              hipStream_t stream) {
    const float* xq   = (const float*)d_in[0];
    const float* xc   = (const float*)d_in[1];
    const int*   eq   = (const int*)d_in[2];
    const int*   ec   = (const int*)d_in[3];
    const float* W1   = (const float*)d_in[4];
    const float* b1   = (const float*)d_in[5];
    const float* W2   = (const float*)d_in[6];
    const float* b2   = (const float*)d_in[7];
    const float* W3   = (const float*)d_in[8];
    const float* b3   = (const float*)d_in[9];
    const float* Watt = (const float*)d_in[10];
    const float* ntnW = (const float*)d_in[11];
    const float* ntnV = (const float*)d_in[12];
    const float* ntnb = (const float*)d_in[13];
    const float* fc1W = (const float*)d_in[14];
    const float* fc1b = (const float*)d_in[15];
    const float* fc2W = (const float*)d_in[16];
    const float* fc2b = (const float*)d_in[17];
    float* out = (float*)d_out;
    float* ws  = (float*)d_ws;

    // ---- workspace layout (float indices), round-0 proven footprint ----
    float* O3   = ws;                           // 2*B*N*32  = 2097152
    float* e12  = O3 + 2097152;                 // 2*B*32    = 8192
    float* bmin = e12 + 8192;                   // 2048 (unused, layout keep)
    float* bmax = bmin + 2048;                  // 2048 (unused, layout keep)
    unsigned int* lohiE = (unsigned int*)(bmax + 2048);  // 2 encoded uints
    float* cntw = (float*)(lohiE + 2);          // 16
    int*   off  = (int*)(ws + 2109504);         // 2B*257 = 65792
    int*   srcs = off + 65792;                  // 2B*E = 524288
    float* wts  = (float*)(srcs + 524288);      // 524288
    float* O1   = ws + 3223872;                 // 2*B*N*128 = 8388608
    float* O2   = O1 + 8388608;                 // 2*B*N*64  = 4194304

    float* O3Q = O3;
    float* O3C = O3 + (size_t)BB * NN * 32;
    float* e1w = e12;
    float* e2w = e12 + BB * 32;
    (void)bmin; (void)bmax;

    csr_kernel<<<2 * BB, 256, 0, stream>>>(eq, ec, off, srcs, wts, lohiE, cntw);

    gcn_fused8<128, 128, true, 1><<<4 * 2 * BB, 512, 0, stream>>>(
        xq, xc, W1, b1, off, srcs, wts, O1);
    gcn_fused8<128, 64, true, 1><<<2 * 2 * BB, 512, 0, stream>>>(
        O1, O1 + (size_t)BB * NN * 128, W2, b2, off, srcs, wts, O2);
    gcn_fused8<64, 32, false, 2><<<2 * 2 * BB, 512, 0, stream>>>(
        O2, O2 + (size_t)BB * NN * 64, W3, b3, off, srcs, wts, O3);

    attpool_kernel<<<2 * BB, 256, 0, stream>>>(O3, Watt, e12);

    pairdot_minmax<<<BB * 4, 256, 0, stream>>>(O3Q, O3C, lohiE);
    pairdot_hist<<<BB * 4, 256, 0, stream>>>(O3Q, O3C, lohiE, cntw);

    final_kernel<<<BB, 256, 0, stream>>>(e1w, e2w, ntnW, ntnV, ntnb, cntw,
                                         fc1W, fc1b, fc2W, fc2b, out);
}